// Round 12
// baseline (238.506 us; speedup 1.0000x reference)
//
#include <hip/hip_runtime.h>
#include <cstdint>
#include <cstddef>

#define TOKENS 4096
#define DM 512
#define DF 2048
#define NE 8
#define NPAIR 8192  // TOKENS * TOPK

typedef unsigned short u16;
typedef __attribute__((ext_vector_type(8))) short short8;
typedef __attribute__((ext_vector_type(4))) float f32x4;

// fp32 -> bf16 round-to-nearest-even (finite inputs only)
__device__ __forceinline__ u16 f2b(float x) {
  uint32_t u = __builtin_bit_cast(uint32_t, x);
  uint32_t r = (u + 0x7fffu + ((u >> 16) & 1u)) >> 16;
  return (u16)r;
}

__device__ __forceinline__ void gl_lds16(const void* gsrc, void* ldst) {
  __builtin_amdgcn_global_load_lds(
      (__attribute__((address_space(1))) void*)(gsrc),
      (__attribute__((address_space(3))) void*)(ldst), 16, 0, 0);
}

// ---------------- prep: routing(+coef)+tilelist | hidden cvt | tr wi ----------------
__global__ __launch_bounds__(256) void prep_kernel(
    const int* __restrict__ eidx, const float* __restrict__ prob,
    const float* __restrict__ hidden, u16* __restrict__ hidden_b,
    const float* __restrict__ wi, u16* __restrict__ wi_t,
    int* __restrict__ pair_token, int* __restrict__ pair_pos,
    float* __restrict__ pair_coef,
    int* __restrict__ seg_off, int* __restrict__ seg_cnt,
    int* __restrict__ tl_e, int* __restrict__ tl_mt) {
  __shared__ __align__(16) float t[64][65];
  int bid = blockIdx.x;
  int tid = threadIdx.x;
  if (bid == 0) {
    int* cnt = (int*)&t[0][0];
    int* off = cnt + 8;
    int* cur = cnt + 16;
    if (tid < NE) { cnt[tid] = 0; cur[tid] = 0; }
    __syncthreads();
    for (int i = tid; i < NPAIR; i += 256) atomicAdd(&cnt[eidx[i]], 1);
    __syncthreads();
    if (tid == 0) {
      int a = 0;
      for (int e = 0; e < NE; ++e) { off[e] = a; a += cnt[e]; }
      int n = 0;
      for (int e = 0; e < NE; ++e) {
        int ntl = (cnt[e] + 127) >> 7;
        for (int m = 0; m < ntl && n < 128; ++m, ++n) { tl_e[n] = e; tl_mt[n] = m; }
      }
      for (; n < 128; ++n) { tl_e[n] = -1; tl_mt[n] = 0; }
    }
    __syncthreads();
    for (int i = tid; i < NPAIR; i += 256) {
      int e = eidx[i];
      int p = off[e] + atomicAdd(&cur[e], 1);
      pair_token[p] = i >> 1;  // token index
      pair_pos[i] = p;         // where this (token,k) landed
      pair_coef[p] = ((i & 1) ? 0.25f : 0.5f) * prob[i];  // df[k]*prob (R7-proven)
    }
    if (tid < NE) { seg_off[tid] = off[tid]; seg_cnt[tid] = cnt[tid]; }
  } else if (bid <= 2048) {
    int i = (bid - 1) * 256 + tid;  // float4 group
    float4 v = ((const float4*)hidden)[i];
    ushort4 o;
    o.x = f2b(v.x); o.y = f2b(v.y); o.z = f2b(v.z); o.w = f2b(v.w);
    ((ushort4*)hidden_b)[i] = o;
  } else {
    const int R = DM, C = DF;
    int f = bid - 2049;
    int e = f >> 8;
    int cb = (f & 31) * 64, rb = ((f >> 5) & 7) * 64;
    const float* s = wi + (size_t)e * R * C;
    u16* d = wi_t + (size_t)e * R * C;
    int r = tid >> 4, cq = tid & 15;
#pragma unroll
    for (int i = 0; i < 4; ++i) {
      float4 v = *(const float4*)&s[(size_t)(rb + r + 16 * i) * C + cb + cq * 4];
      t[r + 16 * i][cq * 4 + 0] = v.x;
      t[r + 16 * i][cq * 4 + 1] = v.y;
      t[r + 16 * i][cq * 4 + 2] = v.z;
      t[r + 16 * i][cq * 4 + 3] = v.w;
    }
    __syncthreads();
    int rq = tid & 15, c0 = tid >> 4;
#pragma unroll
    for (int i = 0; i < 4; ++i) {
      int c = c0 + 16 * i;
      ushort4 o;
      o.x = f2b(t[rq * 4 + 0][c]);
      o.y = f2b(t[rq * 4 + 1][c]);
      o.z = f2b(t[rq * 4 + 2][c]);
      o.w = f2b(t[rq * 4 + 3][c]);
      *(ushort4*)&d[(size_t)(cb + c) * R + rb + rq * 4] = o;
    }
  }
}

// ---------------- GEMM1 (R11-verbatim): BK=64 XOR-swizzle + fused tr_wo z-planes ----
__global__ __launch_bounds__(256) void gemm1_kernel(
    const u16* __restrict__ A,         // hidden_b [4096][512]
    const u16* __restrict__ Bt,        // wi_t [NE][2048][512]
    const int* __restrict__ pair_token,
    const int* __restrict__ seg_off, const int* __restrict__ seg_cnt,
    const int* __restrict__ tl_e, const int* __restrict__ tl_mt,
    u16* __restrict__ out_b,           // act
    const float* __restrict__ tr_src, u16* __restrict__ tr_dst) {
  __shared__ __align__(16) char smem[32768];
  if (blockIdx.z > 0) {
    int flat = (blockIdx.z - 1) * 1152 + blockIdx.y * 16 + blockIdx.x;
    if (flat < 2048) {
      const int R = DF, C = DM;
      float(*t)[65] = (float(*)[65])smem;
      int tid = threadIdx.x;
      int e = flat >> 8;
      int cb = (flat & 7) * 64, rb = ((flat >> 3) & 31) * 64;
      const float* s = tr_src + (size_t)e * R * C;
      u16* d = tr_dst + (size_t)e * R * C;
      int r = tid >> 4, cq = tid & 15;
#pragma unroll
      for (int i = 0; i < 4; ++i) {
        float4 v = *(const float4*)&s[(size_t)(rb + r + 16 * i) * C + cb + cq * 4];
        t[r + 16 * i][cq * 4 + 0] = v.x;
        t[r + 16 * i][cq * 4 + 1] = v.y;
        t[r + 16 * i][cq * 4 + 2] = v.z;
        t[r + 16 * i][cq * 4 + 3] = v.w;
      }
      __syncthreads();
      int rq = tid & 15, c0 = tid >> 4;
#pragma unroll
      for (int i = 0; i < 4; ++i) {
        int c = c0 + 16 * i;
        ushort4 o;
        o.x = f2b(t[rq * 4 + 0][c]);
        o.y = f2b(t[rq * 4 + 1][c]);
        o.z = f2b(t[rq * 4 + 2][c]);
        o.w = f2b(t[rq * 4 + 3][c]);
        *(ushort4*)&d[(size_t)(cb + c) * R + rb + rq * 4] = o;
      }
    }
    return;
  }
  const int e = tl_e[blockIdx.y];
  if (e < 0) return;
  const int mt = tl_mt[blockIdx.y];
  const int cnt = seg_cnt[e];
  const int off = seg_off[e];
  const int nt = blockIdx.x;
  const int tid = threadIdx.x;
  const int wave = tid >> 6, lane = tid & 63;

  u16* Al = (u16*)smem;             // [128][64] bf16, chunk-swizzled
  u16* Bl = (u16*)(smem + 16384);

  const int r0 = wave * 32;
  const int cidx = lane & 7;
  const int rsub = lane >> 3;
  const int csrc = (cidx ^ rsub) * 8;

  const u16* aSrc[4];
  const u16* bSrc[4];
  u16* aDst[4];
  u16* bDst[4];
  const u16* BtBase = Bt + ((size_t)e * DF + (size_t)nt * 128) * DM;
#pragma unroll
  for (int g = 0; g < 4; ++g) {
    int rl = r0 + 8 * g + rsub;
    int m = mt * 128 + rl;
    if (m > cnt - 1) m = cnt - 1;
    int srow = pair_token[off + m];
    aSrc[g] = A + (size_t)srow * DM + csrc;
    bSrc[g] = BtBase + (size_t)rl * DM + csrc;
    aDst[g] = Al + (r0 + 8 * g) * 64;
    bDst[g] = Bl + (r0 + 8 * g) * 64;
  }

  const int wm = wave >> 1, wn = wave & 1;
  const int rl16 = lane & 15;
  const int q = lane >> 4;
  const int rx = rl16 & 7;

  f32x4 acc[4][4];
#pragma unroll
  for (int i = 0; i < 4; ++i)
#pragma unroll
    for (int j = 0; j < 4; ++j)
#pragma unroll
      for (int r = 0; r < 4; ++r) acc[i][j][r] = 0.0f;

  for (int k0 = 0; k0 < DM; k0 += 64) {
#pragma unroll
    for (int g = 0; g < 4; ++g) {
      gl_lds16(aSrc[g] + k0, aDst[g]);
      gl_lds16(bSrc[g] + k0, bDst[g]);
    }
    __syncthreads();
#pragma unroll
    for (int hb = 0; hb < 2; ++hb) {
      const int jofs = ((q + 4 * hb) ^ rx) * 8;
      short8 af[4], bf[4];
#pragma unroll
      for (int mi = 0; mi < 4; ++mi)
        af[mi] = *(const short8*)&Al[(wm * 64 + mi * 16 + rl16) * 64 + jofs];
#pragma unroll
      for (int ni = 0; ni < 4; ++ni)
        bf[ni] = *(const short8*)&Bl[(wn * 64 + ni * 16 + rl16) * 64 + jofs];
#pragma unroll
      for (int mi = 0; mi < 4; ++mi)
#pragma unroll
        for (int ni = 0; ni < 4; ++ni)
          acc[mi][ni] = __builtin_amdgcn_mfma_f32_16x16x32_bf16(af[mi], bf[ni], acc[mi][ni], 0, 0, 0);
    }
    __syncthreads();
  }

  const int rowq = (lane >> 4) * 4;
#pragma unroll
  for (int mi = 0; mi < 4; ++mi) {
#pragma unroll
    for (int r = 0; r < 4; ++r) {
      int m = mt * 128 + wm * 64 + mi * 16 + rowq + r;
      if (m < cnt) {
        size_t rowp = (size_t)(off + m) * DF;
#pragma unroll
        for (int ni = 0; ni < 4; ++ni) {
          int n = nt * 128 + wn * 64 + ni * 16 + rl16;
          float v = acc[mi][ni][r];
          v = v > 0.0f ? v : 0.0f;
          out_b[rowp + n] = f2b(v);
        }
      }
    }
  }
}

// ---------------- GEMM2: 512 threads, in-block split-K halves, coef-scaled write ----
// Each half (waves 0-3 / 4-7) runs the R11-proven 128x128/BK=64-swizzled loop on its
// own 32KB LDS region over K half [half*1024, +1024). Reduction: half1 dumps acc to
// LDS (2 rounds x 64 rows, stride 130 f32 -> 2-way bank = free), half0 adds, applies
// pair_coef, writes Yp[p][n] f32 once. No global partials.
__global__ __launch_bounds__(512) void gemm2_kernel(
    const u16* __restrict__ act,       // [8192][2048] bf16
    const u16* __restrict__ Bt,        // wo_t [NE][512][2048] bf16
    const float* __restrict__ pair_coef,
    const int* __restrict__ seg_off, const int* __restrict__ seg_cnt,
    const int* __restrict__ tl_e, const int* __restrict__ tl_mt,
    float* __restrict__ Yp) {          // [8192][512] f32, coef-applied
  __shared__ __align__(16) char smem[65536];
  const int e = tl_e[blockIdx.y];
  if (e < 0) return;
  const int mt = tl_mt[blockIdx.y];
  const int cnt = seg_cnt[e];
  const int off = seg_off[e];
  const int nt = blockIdx.x;           // 0..3
  const int tid = threadIdx.x;         // 0..511
  const int half = tid >> 8;           // K-half 0/1
  const int wave = (tid >> 6) & 3;     // wave within half
  const int lane = tid & 63;
  const int kb = half * (DF / 2);      // 0 or 1024

  u16* Al = (u16*)(smem + half * 32768);
  u16* Bl = (u16*)(smem + half * 32768 + 16384);

  const int r0 = wave * 32;
  const int cidx = lane & 7;
  const int rsub = lane >> 3;
  const int csrc = (cidx ^ rsub) * 8;

  const u16* aSrc[4];
  const u16* bSrc[4];
  u16* aDst[4];
  u16* bDst[4];
  const u16* BtBase = Bt + ((size_t)e * DM + (size_t)nt * 128) * DF;
#pragma unroll
  for (int g = 0; g < 4; ++g) {
    int rl = r0 + 8 * g + rsub;
    int m = mt * 128 + rl;
    if (m > cnt - 1) m = cnt - 1;
    aSrc[g] = act + (size_t)(off + m) * DF + csrc;
    bSrc[g] = BtBase + (size_t)rl * DF + csrc;
    aDst[g] = Al + (r0 + 8 * g) * 64;
    bDst[g] = Bl + (r0 + 8 * g) * 64;
  }

  const int wm = wave >> 1, wn = wave & 1;
  const int rl16 = lane & 15;
  const int q = lane >> 4;
  const int rx = rl16 & 7;

  f32x4 acc[4][4];
#pragma unroll
  for (int i = 0; i < 4; ++i)
#pragma unroll
    for (int j = 0; j < 4; ++j)
#pragma unroll
      for (int r = 0; r < 4; ++r) acc[i][j][r] = 0.0f;

  for (int k0 = kb; k0 < kb + DF / 2; k0 += 64) {
#pragma unroll
    for (int g = 0; g < 4; ++g) {
      gl_lds16(aSrc[g] + k0, aDst[g]);
      gl_lds16(bSrc[g] + k0, bDst[g]);
    }
    __syncthreads();
#pragma unroll
    for (int hb = 0; hb < 2; ++hb) {
      const int jofs = ((q + 4 * hb) ^ rx) * 8;
      short8 af[4], bf[4];
#pragma unroll
      for (int mi = 0; mi < 4; ++mi)
        af[mi] = *(const short8*)&Al[(wm * 64 + mi * 16 + rl16) * 64 + jofs];
#pragma unroll
      for (int ni = 0; ni < 4; ++ni)
        bf[ni] = *(const short8*)&Bl[(wn * 64 + ni * 16 + rl16) * 64 + jofs];
#pragma unroll
      for (int mi = 0; mi < 4; ++mi)
#pragma unroll
        for (int ni = 0; ni < 4; ++ni)
          acc[mi][ni] = __builtin_amdgcn_mfma_f32_16x16x32_bf16(af[mi], bf[ni], acc[mi][ni], 0, 0, 0);
    }
    __syncthreads();
  }

  // in-block reduction of the two K-halves; rounds over wm to fit 64x130 f32 in LDS
  float* red = (float*)smem;           // [64][130] f32 = 33280 B (tiles are dead now)
  const int rowq = (lane >> 4) * 4;
#pragma unroll
  for (int round = 0; round < 2; ++round) {
    __syncthreads();
    if (half == 1 && wm == round) {
#pragma unroll
      for (int mi = 0; mi < 4; ++mi)
#pragma unroll
        for (int r = 0; r < 4; ++r) {
          int lr = mi * 16 + rowq + r;  // 0..63
#pragma unroll
          for (int ni = 0; ni < 4; ++ni)
            red[lr * 130 + wn * 64 + ni * 16 + rl16] = acc[mi][ni][r];
        }
    }
    __syncthreads();
    if (half == 0 && wm == round) {
#pragma unroll
      for (int mi = 0; mi < 4; ++mi)
#pragma unroll
        for (int r = 0; r < 4; ++r) {
          int lr = mi * 16 + rowq + r;
          int m = mt * 128 + round * 64 + lr;
          if (m < cnt) {
            int p = off + m;
            float cf = pair_coef[p];
            float* rowp = Yp + (size_t)p * DM;
#pragma unroll
            for (int ni = 0; ni < 4; ++ni) {
              int n = nt * 128 + wn * 64 + ni * 16 + rl16;
              rowp[n] = cf * (acc[mi][ni][r] + red[lr * 130 + wn * 64 + ni * 16 + rl16]);
            }
          }
        }
    }
  }
}

// ---------------- combine: out = where(Y[p0]+Y[p1] != 0, ., hidden) ----------------
__global__ void combine_kernel(const float* __restrict__ hidden,
                               const int* __restrict__ pair_pos,
                               const float* __restrict__ Yp,
                               float* __restrict__ out) {
  int i = blockIdx.x * 256 + threadIdx.x;  // float4 group
  int t = i >> 7, g = i & 127;
  int p0 = pair_pos[2 * t], p1 = pair_pos[2 * t + 1];
  float4 a = ((const float4*)(Yp + (size_t)p0 * DM))[g];
  float4 b = ((const float4*)(Yp + (size_t)p1 * DM))[g];
  float4 h = ((const float4*)hidden)[i];
  float4 r, o;
  r.x = a.x + b.x;
  r.y = a.y + b.y;
  r.z = a.z + b.z;
  r.w = a.w + b.w;
  o.x = (r.x != 0.0f) ? r.x : h.x;
  o.y = (r.y != 0.0f) ? r.y : h.y;
  o.z = (r.z != 0.0f) ? r.z : h.z;
  o.w = (r.w != 0.0f) ? r.w : h.w;
  ((float4*)out)[i] = o;
}

extern "C" void kernel_launch(void* const* d_in, const int* in_sizes, int n_in,
                              void* d_out, int out_size, void* d_ws, size_t ws_size,
                              hipStream_t stream) {
  const float* hidden = (const float*)d_in[0];
  const float* prob = (const float*)d_in[1];
  const float* wi = (const float*)d_in[2];
  const float* wo = (const float*)d_in[3];
  const int* eidx = (const int*)d_in[4];
  float* out = (float*)d_out;

  char* ws = (char*)d_ws;
  u16* hidden_b = (u16*)(ws + 0);                     //  4 MB [4096][512] bf16
  u16* wi_t = (u16*)(ws + ((size_t)4 << 20));         // 16 MB [8][2048][512] bf16 (wi^T)
  u16* wo_t = (u16*)(ws + ((size_t)20 << 20));        // 16 MB [8][512][2048] bf16 (wo^T)
  u16* act = (u16*)(ws + ((size_t)36 << 20));         // 32 MB [8192][2048] bf16
  float* Yp = (float*)(ws + ((size_t)68 << 20));      // 16 MB [8192][512] f32, coef-applied
  char* smalls = ws + ((size_t)132 << 20);
  int* pair_token = (int*)(smalls);
  int* pair_pos = (int*)(smalls + (64u << 10));
  int* seg_off = (int*)(smalls + (128u << 10));
  int* seg_cnt = (int*)(smalls + (128u << 10) + 256);
  int* tl_e = (int*)(smalls + (129u << 10));          // 128 ints
  int* tl_mt = (int*)(smalls + (129u << 10) + 512);   // 128 ints
  float* pair_coef = (float*)(smalls + (130u << 10)); // 32 KB

  // 1) prep: routing(+coef)+tilelist | hidden cvt | tr wi
  hipLaunchKernelGGL(prep_kernel, dim3(4097), dim3(256), 0, stream,
                     eidx, prob, hidden, hidden_b, wi, wi_t,
                     pair_token, pair_pos, pair_coef, seg_off, seg_cnt, tl_e, tl_mt);
  // 2) GEMM1 (z=0): act = relu(hidden @ wi[e]); + fused wo transpose (z=1,2)
  hipLaunchKernelGGL(gemm1_kernel, dim3(16, 72, 3), dim3(256), 0, stream,
                     hidden_b, wi_t, pair_token, seg_off, seg_cnt, tl_e, tl_mt,
                     act, wo, wo_t);
  // 3) GEMM2: Yp[p] = coef[p] * (act @ wo[e])[p]; in-block split-K, no partials
  hipLaunchKernelGGL(gemm2_kernel, dim3(4, 72, 1), dim3(512), 0, stream,
                     act, wo_t, pair_coef, seg_off, seg_cnt, tl_e, tl_mt, Yp);
  // 4) combine: out = where(Y[p0]+Y[p1] != 0, ., hidden)
  hipLaunchKernelGGL(combine_kernel, dim3(2048), dim3(256), 0, stream,
                     hidden, pair_pos, Yp, out);
}

// Round 13
// 209.505 us; speedup vs baseline: 1.1384x; 1.1384x over previous
//
#include <hip/hip_runtime.h>
#include <cstdint>
#include <cstddef>

#define TOKENS 4096
#define DM 512
#define DF 2048
#define NE 8
#define NPAIR 8192  // TOKENS * TOPK
#define SPLIT 2     // split-K factor for GEMM2 (f32 partials)

typedef unsigned short u16;
typedef __attribute__((ext_vector_type(8))) short short8;
typedef __attribute__((ext_vector_type(4))) float f32x4;

// fp32 -> bf16 round-to-nearest-even (finite inputs only)
__device__ __forceinline__ u16 f2b(float x) {
  uint32_t u = __builtin_bit_cast(uint32_t, x);
  uint32_t r = (u + 0x7fffu + ((u >> 16) & 1u)) >> 16;
  return (u16)r;
}

__device__ __forceinline__ void gl_lds16(const void* gsrc, void* ldst) {
  __builtin_amdgcn_global_load_lds(
      (__attribute__((address_space(1))) void*)(gsrc),
      (__attribute__((address_space(3))) void*)(ldst), 16, 0, 0);
}

// ---------------- prep: routing+tilelist | hidden cvt | tr wi (R11-verbatim) ----
__global__ __launch_bounds__(256) void prep_kernel(
    const int* __restrict__ eidx, const float* __restrict__ hidden, u16* __restrict__ hidden_b,
    const float* __restrict__ wi, u16* __restrict__ wi_t,
    int* __restrict__ pair_token, int* __restrict__ pair_pos,
    int* __restrict__ seg_off, int* __restrict__ seg_cnt,
    int* __restrict__ tl_e, int* __restrict__ tl_mt) {
  __shared__ __align__(16) float t[64][65];
  int bid = blockIdx.x;
  int tid = threadIdx.x;
  if (bid == 0) {
    int* cnt = (int*)&t[0][0];
    int* off = cnt + 8;
    int* cur = cnt + 16;
    if (tid < NE) { cnt[tid] = 0; cur[tid] = 0; }
    __syncthreads();
    for (int i = tid; i < NPAIR; i += 256) atomicAdd(&cnt[eidx[i]], 1);
    __syncthreads();
    if (tid == 0) {
      int a = 0;
      for (int e = 0; e < NE; ++e) { off[e] = a; a += cnt[e]; }
      int n = 0;
      for (int e = 0; e < NE; ++e) {
        int ntl = (cnt[e] + 127) >> 7;
        for (int m = 0; m < ntl && n < 128; ++m, ++n) { tl_e[n] = e; tl_mt[n] = m; }
      }
      for (; n < 128; ++n) { tl_e[n] = -1; tl_mt[n] = 0; }
    }
    __syncthreads();
    for (int i = tid; i < NPAIR; i += 256) {
      int e = eidx[i];
      int p = off[e] + atomicAdd(&cur[e], 1);
      pair_token[p] = i >> 1;  // token index
      pair_pos[i] = p;         // where this (token,k) landed
    }
    if (tid < NE) { seg_off[tid] = off[tid]; seg_cnt[tid] = cnt[tid]; }
  } else if (bid <= 2048) {
    int i = (bid - 1) * 256 + tid;  // float4 group
    float4 v = ((const float4*)hidden)[i];
    ushort4 o;
    o.x = f2b(v.x); o.y = f2b(v.y); o.z = f2b(v.z); o.w = f2b(v.w);
    ((ushort4*)hidden_b)[i] = o;
  } else {
    const int R = DM, C = DF;
    int f = bid - 2049;
    int e = f >> 8;
    int cb = (f & 31) * 64, rb = ((f >> 5) & 7) * 64;
    const float* s = wi + (size_t)e * R * C;
    u16* d = wi_t + (size_t)e * R * C;
    int r = tid >> 4, cq = tid & 15;
#pragma unroll
    for (int i = 0; i < 4; ++i) {
      float4 v = *(const float4*)&s[(size_t)(rb + r + 16 * i) * C + cb + cq * 4];
      t[r + 16 * i][cq * 4 + 0] = v.x;
      t[r + 16 * i][cq * 4 + 1] = v.y;
      t[r + 16 * i][cq * 4 + 2] = v.z;
      t[r + 16 * i][cq * 4 + 3] = v.w;
    }
    __syncthreads();
    int rq = tid & 15, c0 = tid >> 4;
#pragma unroll
    for (int i = 0; i < 4; ++i) {
      int c = c0 + 16 * i;
      ushort4 o;
      o.x = f2b(t[rq * 4 + 0][c]);
      o.y = f2b(t[rq * 4 + 1][c]);
      o.z = f2b(t[rq * 4 + 2][c]);
      o.w = f2b(t[rq * 4 + 3][c]);
      *(ushort4*)&d[(size_t)(cb + c) * R + rb + rq * 4] = o;
    }
  }
}

// ---------------- GEMM1 (R11-verbatim): BK=64 XOR-swizzle + fused tr_wo z-planes ----
__global__ __launch_bounds__(256) void gemm1_kernel(
    const u16* __restrict__ A,         // hidden_b [4096][512]
    const u16* __restrict__ Bt,        // wi_t [NE][2048][512]
    const int* __restrict__ pair_token,
    const int* __restrict__ seg_off, const int* __restrict__ seg_cnt,
    const int* __restrict__ tl_e, const int* __restrict__ tl_mt,
    u16* __restrict__ out_b,           // act
    const float* __restrict__ tr_src, u16* __restrict__ tr_dst) {
  __shared__ __align__(16) char smem[32768];
  if (blockIdx.z > 0) {
    int flat = (blockIdx.z - 1) * 1152 + blockIdx.y * 16 + blockIdx.x;
    if (flat < 2048) {
      const int R = DF, C = DM;
      float(*t)[65] = (float(*)[65])smem;
      int tid = threadIdx.x;
      int e = flat >> 8;
      int cb = (flat & 7) * 64, rb = ((flat >> 3) & 31) * 64;
      const float* s = tr_src + (size_t)e * R * C;
      u16* d = tr_dst + (size_t)e * R * C;
      int r = tid >> 4, cq = tid & 15;
#pragma unroll
      for (int i = 0; i < 4; ++i) {
        float4 v = *(const float4*)&s[(size_t)(rb + r + 16 * i) * C + cb + cq * 4];
        t[r + 16 * i][cq * 4 + 0] = v.x;
        t[r + 16 * i][cq * 4 + 1] = v.y;
        t[r + 16 * i][cq * 4 + 2] = v.z;
        t[r + 16 * i][cq * 4 + 3] = v.w;
      }
      __syncthreads();
      int rq = tid & 15, c0 = tid >> 4;
#pragma unroll
      for (int i = 0; i < 4; ++i) {
        int c = c0 + 16 * i;
        ushort4 o;
        o.x = f2b(t[rq * 4 + 0][c]);
        o.y = f2b(t[rq * 4 + 1][c]);
        o.z = f2b(t[rq * 4 + 2][c]);
        o.w = f2b(t[rq * 4 + 3][c]);
        *(ushort4*)&d[(size_t)(cb + c) * R + rb + rq * 4] = o;
      }
    }
    return;
  }
  const int e = tl_e[blockIdx.y];
  if (e < 0) return;
  const int mt = tl_mt[blockIdx.y];
  const int cnt = seg_cnt[e];
  const int off = seg_off[e];
  const int nt = blockIdx.x;
  const int tid = threadIdx.x;
  const int wave = tid >> 6, lane = tid & 63;

  u16* Al = (u16*)smem;             // [128][64] bf16, chunk-swizzled
  u16* Bl = (u16*)(smem + 16384);

  const int r0 = wave * 32;
  const int cidx = lane & 7;
  const int rsub = lane >> 3;
  const int csrc = (cidx ^ rsub) * 8;

  const u16* aSrc[4];
  const u16* bSrc[4];
  u16* aDst[4];
  u16* bDst[4];
  const u16* BtBase = Bt + ((size_t)e * DF + (size_t)nt * 128) * DM;
#pragma unroll
  for (int g = 0; g < 4; ++g) {
    int rl = r0 + 8 * g + rsub;
    int m = mt * 128 + rl;
    if (m > cnt - 1) m = cnt - 1;
    int srow = pair_token[off + m];
    aSrc[g] = A + (size_t)srow * DM + csrc;
    bSrc[g] = BtBase + (size_t)rl * DM + csrc;
    aDst[g] = Al + (r0 + 8 * g) * 64;
    bDst[g] = Bl + (r0 + 8 * g) * 64;
  }

  const int wm = wave >> 1, wn = wave & 1;
  const int rl16 = lane & 15;
  const int q = lane >> 4;
  const int rx = rl16 & 7;

  f32x4 acc[4][4];
#pragma unroll
  for (int i = 0; i < 4; ++i)
#pragma unroll
    for (int j = 0; j < 4; ++j)
#pragma unroll
      for (int r = 0; r < 4; ++r) acc[i][j][r] = 0.0f;

  for (int k0 = 0; k0 < DM; k0 += 64) {
#pragma unroll
    for (int g = 0; g < 4; ++g) {
      gl_lds16(aSrc[g] + k0, aDst[g]);
      gl_lds16(bSrc[g] + k0, bDst[g]);
    }
    __syncthreads();
#pragma unroll
    for (int hb = 0; hb < 2; ++hb) {
      const int jofs = ((q + 4 * hb) ^ rx) * 8;
      short8 af[4], bf[4];
#pragma unroll
      for (int mi = 0; mi < 4; ++mi)
        af[mi] = *(const short8*)&Al[(wm * 64 + mi * 16 + rl16) * 64 + jofs];
#pragma unroll
      for (int ni = 0; ni < 4; ++ni)
        bf[ni] = *(const short8*)&Bl[(wn * 64 + ni * 16 + rl16) * 64 + jofs];
#pragma unroll
      for (int mi = 0; mi < 4; ++mi)
#pragma unroll
        for (int ni = 0; ni < 4; ++ni)
          acc[mi][ni] = __builtin_amdgcn_mfma_f32_16x16x32_bf16(af[mi], bf[ni], acc[mi][ni], 0, 0, 0);
    }
    __syncthreads();
  }

  const int rowq = (lane >> 4) * 4;
#pragma unroll
  for (int mi = 0; mi < 4; ++mi) {
#pragma unroll
    for (int r = 0; r < 4; ++r) {
      int m = mt * 128 + wm * 64 + mi * 16 + rowq + r;
      if (m < cnt) {
        size_t rowp = (size_t)(off + m) * DF;
#pragma unroll
        for (int ni = 0; ni < 4; ++ni) {
          int n = nt * 128 + wn * 64 + ni * 16 + rl16;
          float v = acc[mi][ni][r];
          v = v > 0.0f ? v : 0.0f;
          out_b[rowp + n] = f2b(v);
        }
      }
    }
  }
}

// ---------------- GEMM2: R9-verbatim BK=32 body, global split-K f32 partials ----
// Ypart[sp][p][n] = sum_{k in [sp*ks,+ks)} act[p][k] * wo_t[e][n][k]
// blockIdx.x = (sp << sp_shift) | nt; (e, mt) = tile list.
__global__ __launch_bounds__(256) void gemm2_kernel(
    const u16* __restrict__ A,         // act [8192][2048]
    const u16* __restrict__ Bt,        // wo_t [NE][512][2048]
    const int* __restrict__ seg_off, const int* __restrict__ seg_cnt,
    const int* __restrict__ tl_e, const int* __restrict__ tl_mt,
    float* __restrict__ out_f,
    int nt_mask, int sp_shift, int ks) {
  const int e = tl_e[blockIdx.y];
  if (e < 0) return;
  const int mt = tl_mt[blockIdx.y];
  const int cnt = seg_cnt[e];
  const int off = seg_off[e];
  const int nt = blockIdx.x & nt_mask;
  const int sp = blockIdx.x >> sp_shift;
  const int kb = sp * ks, kend = kb + ks;
  const int tid = threadIdx.x;
  const int wave = tid >> 6, lane = tid & 63;

  __shared__ __align__(16) u16 Al[128 * 32];
  __shared__ __align__(16) u16 Bl[128 * 32];

  const int r0 = wave * 32;
  const int rr = lane >> 2;
  const int cc = (lane & 3) * 8;  // element offset (8 bf16 = 16B)

  const u16* aSrc[2];
  const u16* bSrc[2];
  const u16* BtBase = Bt + ((size_t)e * DM + (size_t)nt * 128) * DF;
#pragma unroll
  for (int g = 0; g < 2; ++g) {
    int rl = r0 + g * 16 + rr;
    int m = mt * 128 + rl;
    if (m > cnt - 1) m = cnt - 1;  // clamp padding rows to valid data
    aSrc[g] = A + (size_t)(off + m) * DF + cc;
    bSrc[g] = BtBase + (size_t)rl * DF + cc;
  }

  const int wm = wave >> 1, wn = wave & 1;
  const int rl16 = lane & 15;
  const int kk = (lane >> 4) * 8;

  f32x4 acc[4][4];
#pragma unroll
  for (int i = 0; i < 4; ++i)
#pragma unroll
    for (int j = 0; j < 4; ++j)
#pragma unroll
      for (int r = 0; r < 4; ++r) acc[i][j][r] = 0.0f;

  for (int k0 = kb; k0 < kend; k0 += 32) {
#pragma unroll
    for (int g = 0; g < 2; ++g) {
      gl_lds16(aSrc[g] + k0, &Al[(r0 + g * 16) * 32]);
      gl_lds16(bSrc[g] + k0, &Bl[(r0 + g * 16) * 32]);
    }
    __syncthreads();
    short8 af[4], bf[4];
#pragma unroll
    for (int mi = 0; mi < 4; ++mi)
      af[mi] = *(const short8*)&Al[(wm * 64 + mi * 16 + rl16) * 32 + kk];
#pragma unroll
    for (int ni = 0; ni < 4; ++ni)
      bf[ni] = *(const short8*)&Bl[(wn * 64 + ni * 16 + rl16) * 32 + kk];
#pragma unroll
    for (int mi = 0; mi < 4; ++mi)
#pragma unroll
      for (int ni = 0; ni < 4; ++ni)
        acc[mi][ni] = __builtin_amdgcn_mfma_f32_16x16x32_bf16(af[mi], bf[ni], acc[mi][ni], 0, 0, 0);
    __syncthreads();
  }

  float* outp = out_f + (size_t)sp * NPAIR * DM;
  const int rowq = (lane >> 4) * 4;
#pragma unroll
  for (int mi = 0; mi < 4; ++mi) {
#pragma unroll
    for (int r = 0; r < 4; ++r) {
      int m = mt * 128 + wm * 64 + mi * 16 + rowq + r;
      if (m < cnt) {
        size_t rowp = (size_t)(off + m) * DM;
#pragma unroll
        for (int ni = 0; ni < 4; ++ni) {
          int n = nt * 128 + wn * 64 + ni * 16 + rl16;
          outp[rowp + n] = acc[mi][ni][r];
        }
      }
    }
  }
}

// ---------------- combine (proven, f32 partials) ----------------
__global__ void combine_kernel(const float* __restrict__ hidden,
                               const float* __restrict__ prob,
                               const int* __restrict__ pair_pos,
                               const float* __restrict__ Ypart,
                               float* __restrict__ out, int nsplit) {
  int i = blockIdx.x * 256 + threadIdx.x;  // group of 4 floats
  int t = i >> 7;                          // 128 groups per token (512/4)
  int g = i & 127;
  int p0 = pair_pos[2 * t], p1 = pair_pos[2 * t + 1];
  float c0 = 0.5f * prob[2 * t];
  float c1 = 0.25f * prob[2 * t + 1];
  float4 a = {0.f, 0.f, 0.f, 0.f}, b = {0.f, 0.f, 0.f, 0.f};
  for (int s = 0; s < nsplit; ++s) {
    const float4* Y = (const float4*)(Ypart + (size_t)s * NPAIR * DM);
    float4 va = Y[(size_t)p0 * 128 + g];
    float4 vb = Y[(size_t)p1 * 128 + g];
    a.x += va.x; a.y += va.y; a.z += va.z; a.w += va.w;
    b.x += vb.x; b.y += vb.y; b.z += vb.z; b.w += vb.w;
  }
  float4 h = ((const float4*)hidden)[i];
  float4 r, o;
  r.x = c0 * a.x + c1 * b.x;
  r.y = c0 * a.y + c1 * b.y;
  r.z = c0 * a.z + c1 * b.z;
  r.w = c0 * a.w + c1 * b.w;
  o.x = (r.x != 0.0f) ? r.x : h.x;
  o.y = (r.y != 0.0f) ? r.y : h.y;
  o.z = (r.z != 0.0f) ? r.z : h.z;
  o.w = (r.w != 0.0f) ? r.w : h.w;
  ((float4*)out)[i] = o;
}

extern "C" void kernel_launch(void* const* d_in, const int* in_sizes, int n_in,
                              void* d_out, int out_size, void* d_ws, size_t ws_size,
                              hipStream_t stream) {
  const float* hidden = (const float*)d_in[0];
  const float* prob = (const float*)d_in[1];
  const float* wi = (const float*)d_in[2];
  const float* wo = (const float*)d_in[3];
  const int* eidx = (const int*)d_in[4];
  float* out = (float*)d_out;

  char* ws = (char*)d_ws;
  u16* hidden_b = (u16*)(ws + 0);                     //  4 MB [4096][512] bf16
  u16* wi_t = (u16*)(ws + ((size_t)4 << 20));         // 16 MB [8][2048][512] bf16 (wi^T)
  u16* wo_t = (u16*)(ws + ((size_t)20 << 20));        // 16 MB [8][512][2048] bf16 (wo^T)
  u16* act = (u16*)(ws + ((size_t)36 << 20));         // 32 MB [8192][2048] bf16
  float* Ypart = (float*)(ws + ((size_t)68 << 20));   // 32 MB [2][8192][512] f32
  char* smalls = ws + ((size_t)132 << 20);
  int* pair_token = (int*)(smalls);
  int* pair_pos = (int*)(smalls + (64u << 10));
  int* seg_off = (int*)(smalls + (128u << 10));
  int* seg_cnt = (int*)(smalls + (128u << 10) + 256);
  int* tl_e = (int*)(smalls + (129u << 10));          // 128 ints
  int* tl_mt = (int*)(smalls + (129u << 10) + 512);   // 128 ints

  // 1) prep: routing+tilelist | hidden cvt | tr wi
  hipLaunchKernelGGL(prep_kernel, dim3(4097), dim3(256), 0, stream,
                     eidx, hidden, hidden_b, wi, wi_t,
                     pair_token, pair_pos, seg_off, seg_cnt, tl_e, tl_mt);
  // 2) GEMM1 (z=0): act = relu(hidden @ wi[e]); + fused wo transpose (z=1,2)
  hipLaunchKernelGGL(gemm1_kernel, dim3(16, 72, 3), dim3(256), 0, stream,
                     hidden_b, wi_t, pair_token, seg_off, seg_cnt, tl_e, tl_mt,
                     act, wo, wo_t);
  // 3) GEMM2: Ypart[sp] = act @ wo[e] (f32 partials); K=2048 split 2; BK=32 body
  hipLaunchKernelGGL(gemm2_kernel, dim3(4 * SPLIT, 72, 1), dim3(256), 0, stream,
                     act, wo_t, seg_off, seg_cnt, tl_e, tl_mt,
                     Ypart, 3, 2, DF / SPLIT);
  // 4) combine + where(next!=0, next, hidden)
  hipLaunchKernelGGL(combine_kernel, dim3(2048), dim3(256), 0, stream,
                     hidden, prob, pair_pos, Ypart, out, SPLIT);
}